// Round 10
// baseline (555.680 us; speedup 1.0000x reference)
//
#include <hip/hip_runtime.h>

#define SEQ_LEN 96
#define PRED_LEN 16
#define HIDDEN 64
#define FEAT 7
#define BATCH 512
#define TL (SEQ_LEN + PRED_LEN)   // 112-row sliding timeline
#define XSTR 8                    // padded row stride (f32 timeline)

typedef float    v2f __attribute__((ext_vector_type(2)));
typedef _Float16 v2h __attribute__((ext_vector_type(2)));
typedef _Float16 v8h __attribute__((ext_vector_type(8)));

#define L2E 1.4426950408889634f

// v_dot2_f32_f16: a.x*b.x + a.y*b.y + c  (2 MACs/inst, fp32 accumulate)
#if __has_builtin(__builtin_amdgcn_fdot2)
#define FDOT2(a, b, c) __builtin_amdgcn_fdot2((a), (b), (c), false)
#else
#define FDOT2(a, b, c) fmaf((float)(a)[0], (float)(b)[0], \
                        fmaf((float)(a)[1], (float)(b)[1], (c)))
#endif

// DPP pair-swap (0<->1, 2<->3, ...): quad_perm [1,0,3,2]. Pure VALU.
__device__ __forceinline__ float qp_xor1(float v) {
    return __int_as_float(__builtin_amdgcn_mov_dpp(__float_as_int(v), 0xB1, 0xF, 0xF, true));
}

// r9 config (best: 539us) with the weight set shrunk to f16:
//  - W_hh per thread: 128 f32 -> 64 f16x2 VGPRs. Kills the 132-VGPR demotion
//    wall (5 rounds of evidence: fp32-128 ALWAYS demotes, ~120 copy insts/step).
//  - h stored in LDS as f16: h-broadcast reads halve to 4 ds_read_b128, pairs
//    feed v_dot2_f32_f16 directly (no repack).
//  - Everything else fp32: x path, accumulators, c, activations, outputs.
// Block = 128 threads (2 waves) = ONE batch; grid 512 -> 2 blocks/CU with
// staggered barriers (r8 lesson), 1 wave/SIMD (r6 lesson). Thread (u=tid>>1,
// s=tid&1): all 4 gates of unit u, K-half [32s,32s+32). One barrier/step;
// x-prefetch in the barrier shadow (r9 win).
__global__ __launch_bounds__(128)
__attribute__((amdgpu_waves_per_eu(1, 1)))
void lstm_ar_kernel(
    const float* __restrict__ x,     // [B, 96, 7]
    const float* __restrict__ W_ih,  // [256, 7]
    const float* __restrict__ W_hh,  // [256, 64]
    const float* __restrict__ b_ih,  // [256]
    const float* __restrict__ b_hh,  // [256]
    const float* __restrict__ fc_W,  // [7, 64]
    const float* __restrict__ fc_b,  // [7]
    float* __restrict__ out)         // [B, 16, 7]
{
    __shared__ float xs[TL * XSTR];               // f32 sliding timeline (pad=0)
    __shared__ __align__(16) _Float16 hraw[2][HIDDEN];  // f16 h ping-pong
    __shared__ float fcw[FEAT * HIDDEN];
    __shared__ float fcb[FEAT];

    const int tid = threadIdx.x;
    const int b   = blockIdx.x;
    const int u   = tid >> 1;         // hidden unit 0..63
    const int s   = tid & 1;          // K-half / activation-role

    // ---- per-thread weights: 4 gates x 32 K-cols as 16 f16x2 each ----
    v2h wh[4][16];
    #pragma unroll
    for (int g = 0; g < 4; ++g) {
        const float* wr = W_hh + (u + (g << 6)) * HIDDEN + (s << 5);
        #pragma unroll
        for (int m = 0; m < 16; ++m) {
            v2h t;
            t[0] = (_Float16)wr[2 * m];      // RNE cvt
            t[1] = (_Float16)wr[2 * m + 1];
            wh[g][m] = t;
        }
    }
    v2f wx[4][2];                     // x-cols [4s,4s+4) f32; col 7 -> 0 (eats pad)
    #pragma unroll
    for (int g = 0; g < 4; ++g)
        #pragma unroll
        for (int i = 0; i < 2; ++i) {
            int c0 = (s << 2) + 2 * i, c1 = c0 + 1;
            wx[g][i].x = W_ih[(u + (g << 6)) * FEAT + c0];
            wx[g][i].y = (c1 < FEAT) ? W_ih[(u + (g << 6)) * FEAT + c1] : 0.0f;
        }
    float bias[4];                    // bias carried by s==0 only
    #pragma unroll
    for (int g = 0; g < 4; ++g)
        bias[g] = (s == 0) ? (b_ih[u + (g << 6)] + b_hh[u + (g << 6)]) : 0.0f;

    // act_b per-lane consts: s=0 -> gate o (sigmoid), s=1 -> gate g (tanh)
    const float bk  = (s == 1) ? (-2.0f * L2E) : (-L2E);
    const float bm  = (s == 1) ? 2.0f : 1.0f;
    const float bbc = (s == 1) ? -1.0f : 0.0f;

    // ---- stage timeline / fc / init ----
    for (int i = tid; i < TL * XSTR; i += 128) {
        int row = i >> 3, f = i & 7;
        float v = 0.0f;
        if (row < SEQ_LEN && f < FEAT) v = x[b * SEQ_LEN * FEAT + row * FEAT + f];
        xs[i] = v;
    }
    for (int i = tid; i < FEAT * HIDDEN; i += 128) fcw[i] = fc_W[i];
    if (tid < FEAT)   fcb[tid] = fc_b[tid];
    if (tid < HIDDEN) hraw[0][tid] = (_Float16)0.0f;
    float c = 0.0f;                   // c_u replica (identical in both pair lanes)
    __syncthreads();

    // One step: consumes prefetched xv, reads h (f16), writes h (f16),
    // prefetches x row `nrow` before the barrier, returns it.
    auto step = [&](float4 xv, int nrow, int pr, int pw) -> float4 {
        const v8h* h8 = (const v8h*)&hraw[pr][s << 5];

        float a0 = bias[0], a1 = bias[1], a2 = bias[2], a3 = bias[3];
        v2f X0 = {0.0f, 0.0f}, X1 = X0, X2 = X0, X3 = X0;
        v2f xlo; xlo.x = xv.x; xlo.y = xv.y;
        v2f xhi; xhi.x = xv.z; xhi.y = xv.w;
        X0 = __builtin_elementwise_fma(wx[0][0], xlo, X0);
        X1 = __builtin_elementwise_fma(wx[1][0], xlo, X1);
        X2 = __builtin_elementwise_fma(wx[2][0], xlo, X2);
        X3 = __builtin_elementwise_fma(wx[3][0], xlo, X3);
        X0 = __builtin_elementwise_fma(wx[0][1], xhi, X0);
        X1 = __builtin_elementwise_fma(wx[1][1], xhi, X1);
        X2 = __builtin_elementwise_fma(wx[2][1], xhi, X2);
        X3 = __builtin_elementwise_fma(wx[3][1], xhi, X3);

        #pragma unroll
        for (int j = 0; j < 4; ++j) {
            v8h hv = h8[j];                         // 8 h values (f16), one b128
            v2h q0 = __builtin_shufflevector(hv, hv, 0, 1);
            v2h q1 = __builtin_shufflevector(hv, hv, 2, 3);
            v2h q2 = __builtin_shufflevector(hv, hv, 4, 5);
            v2h q3 = __builtin_shufflevector(hv, hv, 6, 7);
            a0 = FDOT2(wh[0][4*j+0], q0, a0);
            a1 = FDOT2(wh[1][4*j+0], q0, a1);
            a2 = FDOT2(wh[2][4*j+0], q0, a2);
            a3 = FDOT2(wh[3][4*j+0], q0, a3);
            a0 = FDOT2(wh[0][4*j+1], q1, a0);
            a1 = FDOT2(wh[1][4*j+1], q1, a1);
            a2 = FDOT2(wh[2][4*j+1], q1, a2);
            a3 = FDOT2(wh[3][4*j+1], q1, a3);
            a0 = FDOT2(wh[0][4*j+2], q2, a0);
            a1 = FDOT2(wh[1][4*j+2], q2, a1);
            a2 = FDOT2(wh[2][4*j+2], q2, a2);
            a3 = FDOT2(wh[3][4*j+2], q2, a3);
            a0 = FDOT2(wh[0][4*j+3], q3, a0);
            a1 = FDOT2(wh[1][4*j+3], q3, a1);
            a2 = FDOT2(wh[2][4*j+3], q3, a2);
            a3 = FDOT2(wh[3][4*j+3], q3, a3);
        }

        // merge x-partials + ONE pair-reduce round
        float r0 = a0 + (X0.x + X0.y);
        float r1 = a1 + (X1.x + X1.y);
        float r2 = a2 + (X2.x + X2.y);
        float r3 = a3 + (X3.x + X3.y);
        r0 += qp_xor1(r0); r1 += qp_xor1(r1);
        r2 += qp_xor1(r2); r3 += qp_xor1(r3);

        // lane roles: s=0 activates f(r1),o(r3); s=1 activates i(r0),g(r2)
        float aa = s ? r0 : r1;                       // sigmoid in both lanes
        float ab = s ? r2 : r3;                       // tanh | sigmoid
        float ea = __builtin_amdgcn_exp2f(aa * (-L2E));
        float va = __builtin_amdgcn_rcpf(1.0f + ea);  // sigmoid(aa)
        float eb = __builtin_amdgcn_exp2f(ab * bk);
        float rb = __builtin_amdgcn_rcpf(1.0f + eb);
        float vb = fmaf(bm, rb, bbc);

        // exchange with partner lane, canonicalize (i,f,g,o)
        float pa = qp_xor1(va);
        float pb = qp_xor1(vb);
        float gi = s ? va : pa;
        float gf = s ? pa : va;
        float gg = s ? vb : pb;
        float go = s ? pb : vb;

        c = fmaf(gf, c, gi * gg);
        float e2 = __builtin_amdgcn_exp2f(c * (-2.0f * L2E));
        float rr = __builtin_amdgcn_rcpf(1.0f + e2);
        float th = fmaf(2.0f, rr, -1.0f);             // tanh(c)
        float h  = go * th;

        hraw[pw][u] = (_Float16)h;    // both pair lanes: same addr, same bits

        // prefetch next x row in the barrier shadow
        float4 nxt = *(const float4*)&xs[nrow * XSTR + (s << 2)];
        __syncthreads();              // the ONLY barrier per step
        return nxt;
    };

    for (int k = 0; k < PRED_LEN; ++k) {
        float4 xv = *(const float4*)&xs[k * XSTR + (s << 2)];   // row k (t=0)
        for (int t = 0; t < SEQ_LEN; t += 2) {
            xv = step(xv, k + t + 1, 0, 1);
            xv = step(xv, k + t + 2, 1, 0);   // t=94 prefetches row k+96 <= 111, in-bounds
        }
        // after 96 steps the latest h is in parity 0

        // ---- prediction head: lanes 0..6 of wave 0 (h: f16 -> f32) ----
        if (tid < FEAT) {
            float p0 = fcb[tid], p1 = 0.0f, p2 = 0.0f, p3 = 0.0f;
            #pragma unroll
            for (int j = 0; j < HIDDEN; j += 4) {
                p0 = fmaf(fcw[tid * HIDDEN + j + 0], (float)hraw[0][j + 0], p0);
                p1 = fmaf(fcw[tid * HIDDEN + j + 1], (float)hraw[0][j + 1], p1);
                p2 = fmaf(fcw[tid * HIDDEN + j + 2], (float)hraw[0][j + 2], p2);
                p3 = fmaf(fcw[tid * HIDDEN + j + 3], (float)hraw[0][j + 3], p3);
            }
            float pred = (p0 + p1) + (p2 + p3);
            out[(b * PRED_LEN + k) * FEAT + tid] = pred;
            xs[(SEQ_LEN + k) * XSTR + tid] = pred;   // append (pad slot stays 0)
        }
        __syncthreads();
    }
}

extern "C" void kernel_launch(void* const* d_in, const int* in_sizes, int n_in,
                              void* d_out, int out_size, void* d_ws, size_t ws_size,
                              hipStream_t stream) {
    const float* x    = (const float*)d_in[0];
    const float* W_ih = (const float*)d_in[1];
    const float* W_hh = (const float*)d_in[2];
    const float* b_ih = (const float*)d_in[3];
    const float* b_hh = (const float*)d_in[4];
    const float* fc_W = (const float*)d_in[5];
    const float* fc_b = (const float*)d_in[6];
    float* out = (float*)d_out;

    lstm_ar_kernel<<<BATCH, 128, 0, stream>>>(x, W_ih, W_hh, b_ih, b_hh, fc_W, fc_b, out);
}